// Round 7
// baseline (7486.691 us; speedup 1.0000x reference)
//
#include <hip/hip_runtime.h>
#include <stdint.h>
#include <stddef.h>

#define S_LEN 512
#define BATCH 256
#define NIN   64
#define HD    512
#define G4    2048   // 4*H
#define RING_D 8     // ring depth (pow2); back-pressure enforced at t-6 (provable bound t-7)
#define BT    64     // batch rows per WG

typedef _Float16 f16;
typedef _Float16 f16x8 __attribute__((ext_vector_type(8)));
typedef float    f32x4 __attribute__((ext_vector_type(4)));
typedef uint32_t u32x4 __attribute__((ext_vector_type(4)));
typedef uint64_t u64x2 __attribute__((ext_vector_type(2)));

// ============================ prep kernels ============================
__global__ void k_f32_to_f16(const float* __restrict__ src, f16* __restrict__ dst, int n) {
  int i = blockIdx.x * 256 + threadIdx.x;
  if (i < n) dst[i] = (f16)src[i];
}

// x [B,S,I] fp32 -> xin [(s*256+b)*64+i] fp16
__global__ void k_x_transpose(const float* __restrict__ x, f16* __restrict__ xin) {
  int idx = blockIdx.x * 256 + threadIdx.x;
  int i  = idx & 63;
  int sb = idx >> 6;
  int b  = sb & 255;
  int s  = sb >> 8;
  xin[idx] = (f16)x[((size_t)b * S_LEN + s) * NIN + i];
}

__global__ void k_zero_i32(uint32_t* p, int n) {
  int i = blockIdx.x * 256 + threadIdx.x;
  if (i < n) p[i] = 0u;
}

// ====================== fused 3-layer systolic LSTM — XCD-local, template-specialized ======================
// Semantics = R6 (correctness-proven on HW: dual-store h to ringL[plain->XCD L2] + ringM[agent->
// MALL]; consumers pick L2 path only if the runtime xcdmap handshake verifies co-XCD placement;
// fallback = MALL path). Structure = R3 (the only no-spill variant: VGPR=128, FETCH 2.2GB).
//
// R4/R5/R6 ALL spilled the 128-VGPR weight set (VGPR_Count 116/88/88, FETCH 9-13GB scratch
// storms) because branchy staging / split MFMA sites inside the time loop merged live ranges.
// Fix here: the WHOLE time loop is a template lstm_loop<LHL,LPM>, dispatched ONCE per WG into
// one of 5 instantiations. Each instantiation is R3's exact straight-line loop body with a
// single staging variant compiled in -> per-arm register allocation identical to R3.
//   LHL: 1 = lh staged from ringL (volatile u64 loads -> sc0/L2), 0 = ringM agent atomics.
//   LPM: 0 = x input (layer0), 1 = prev-h from ringL (volatile), 2 = prev-h from ringM (atomic).
//
// Grid 256 x 512 (64 dummies exit). xcd=blockIdx&7, slot=blockIdx>>3 (HW round-robin):
//   xcd<4 : bi=xcd, l=slot>>4 (0 or 1), gi=slot&15   -> (l0,bi)+(l1,bi) pair per XCD
//   xcd>=4: bi=xcd-4, l=2, gi=slot (<16; else dummy)
// MALL then carries only l2's lhp (4MB/step); lh everywhere + l1's lhp are XCD-L2-served.
template<int LHL, int LPM>
static __device__ __forceinline__ void lstm_loop(
    const int tid, const int lane, const int wave, const int l, const int bi, const int gi,
    const f16* __restrict__ whh_l, const f16* __restrict__ wih_l,
    const float* __restrict__ bias_l, const f16* __restrict__ xin,
    f16* __restrict__ ringM, f16* __restrict__ ringL,
    const int* fown, int* myflag, const int* fprev, const int* fnext,
    f16* __restrict__ hlast, char* smem) {
  const int ln   = lane & 15;
  const int quad = lane >> 4;
  const int g    = wave >> 1;         // gate 0..3
  const int kh   = wave & 1;          // 0: Whh/lh, 1: Wih/lhp

  char*  lh_b  = smem;                   // 64 KiB own h_{t-1} tile (64 rows x 1024B)
  char*  lhp_b = smem + 65536;           // 64 KiB prev h_t tile / x_t tile
  float* lg0   = (float*)smem;           // 32 KiB partial gates (kh=0), aliases lh
  float* lg1   = (float*)(smem + 32768); // 32 KiB partial gates (kh=1), aliases lh

  auto swz = [](int row, int boff) { return row * 1024 + (boff ^ ((row & 7) << 4)); };

  // --- weight fragments -> registers (R3 verbatim; l-dependence is compile-time via LPM) ---
  f16x8 wf[16][2];
  if (kh == 0 || LPM != 0) {
    const f16* W = kh ? wih_l : whh_l;
#pragma unroll
    for (int nb = 0; nb < 2; nb++) {
      const int r = g * 512 + gi * 32 + nb * 16 + ln;   // row in [2048, 512]
#pragma unroll
      for (int ks = 0; ks < 16; ks++) {
        u32x4 tmp = *(const u32x4*)(W + (size_t)r * HD + ks * 32 + quad * 8);
        asm volatile("" : "+v"(tmp));
        wf[ks][nb] = __builtin_bit_cast(f16x8, tmp);
      }
    }
  } else {  // layer0, kh==1: Wih1 is [2048][64]
#pragma unroll
    for (int nb = 0; nb < 2; nb++) {
      const int r = g * 512 + gi * 32 + nb * 16 + ln;
#pragma unroll
      for (int ks = 0; ks < 2; ks++) {
        u32x4 tmp = *(const u32x4*)(wih_l + (size_t)r * NIN + ks * 32 + quad * 8);
        asm volatile("" : "+v"(tmp));
        wf[ks][nb] = __builtin_bit_cast(f16x8, tmp);
      }
    }
  }

  // --- per-thread elementwise state: 4 rows x 1 h-col ---
  const int brow = tid >> 5;
  const int hl_  = tid & 31;
  float cv[4] = {0.f, 0.f, 0.f, 0.f};
  const float bv0 = bias_l[0 * HD + gi * 32 + hl_];
  const float bv1 = bias_l[1 * HD + gi * 32 + hl_];
  const float bv2 = bias_l[2 * HD + gi * 32 + hl_];
  const float bv3 = bias_l[3 * HD + gi * 32 + hl_];

  for (int t = 0; t < S_LEN; t++) {
    // ---- all waves poll (quad roles, R3 verbatim; D=8 -> fnext >= t-6) ----
    {
      const int* fp = fown;
      int need = t;
      if (quad == 1 && LPM != 0)      { fp = fprev; need = t + 1; }
      else if (quad == 2 && l < 2)    { fp = fnext; need = t + 2 - RING_D; }
      int v = __hip_atomic_load(fp + ln, __ATOMIC_RELAXED, __HIP_MEMORY_SCOPE_AGENT);
      while (!__all(v >= need)) {
        __builtin_amdgcn_s_sleep(1);
        v = __hip_atomic_load(fp + ln, __ATOMIC_RELAXED, __HIP_MEMORY_SCOPE_AGENT);
      }
    }
    asm volatile("" ::: "memory");   // keep data loads below the poll

    // ---- stage own h_{t-1} (slot t%D) -> lh ----
    {
      const size_t base = ((size_t)l * RING_D + (t & (RING_D - 1))) * (BATCH * HD)
                        + (size_t)(bi * BT) * HD;
      uint64_t a0[8], a1[8];
      if (LHL) {
        const volatile uint64_t* hown = (const volatile uint64_t*)(ringL + base);
#pragma unroll
        for (int j = 0; j < 8; j++) {
          a0[j] = hown[j * 1024 + tid * 2];
          a1[j] = hown[j * 1024 + tid * 2 + 1];
        }
      } else {
        const uint64_t* hown = (const uint64_t*)(ringM + base);
#pragma unroll
        for (int j = 0; j < 8; j++) {
          a0[j] = __hip_atomic_load(hown + j * 1024 + tid * 2,     __ATOMIC_RELAXED, __HIP_MEMORY_SCOPE_AGENT);
          a1[j] = __hip_atomic_load(hown + j * 1024 + tid * 2 + 1, __ATOMIC_RELAXED, __HIP_MEMORY_SCOPE_AGENT);
        }
      }
      // ---- stage prev h_t (slot (t+1)%D) / x_t -> lhp ----
      if (LPM == 0) {
        const int xr = tid >> 3, xc = tid & 7;   // 64 rows x 8 chunks of 16B
        u32x4 xv = *(const u32x4*)(xin + ((size_t)(t * 256 + bi * BT + xr)) * NIN + xc * 8);
        *(u32x4*)(lhp_b + swz(xr, xc * 16)) = xv;
      } else {
        const size_t pbase = ((size_t)(l - 1) * RING_D + ((t + 1) & (RING_D - 1))) * (BATCH * HD)
                           + (size_t)(bi * BT) * HD;
        uint64_t p0[8], p1[8];
        if (LPM == 1) {
          const volatile uint64_t* hprev = (const volatile uint64_t*)(ringL + pbase);
#pragma unroll
          for (int j = 0; j < 8; j++) {
            p0[j] = hprev[j * 1024 + tid * 2];
            p1[j] = hprev[j * 1024 + tid * 2 + 1];
          }
        } else {
          const uint64_t* hprev = (const uint64_t*)(ringM + pbase);
#pragma unroll
          for (int j = 0; j < 8; j++) {
            p0[j] = __hip_atomic_load(hprev + j * 1024 + tid * 2,     __ATOMIC_RELAXED, __HIP_MEMORY_SCOPE_AGENT);
            p1[j] = __hip_atomic_load(hprev + j * 1024 + tid * 2 + 1, __ATOMIC_RELAXED, __HIP_MEMORY_SCOPE_AGENT);
          }
        }
#pragma unroll
        for (int j = 0; j < 8; j++) {
          const int e = j * 1024 + tid * 2, row = e >> 7, c8 = e & 127;
          u64x2 p; p[0] = p0[j]; p[1] = p1[j];
          *(u64x2*)(lhp_b + swz(row, c8 * 8)) = p;
        }
      }
#pragma unroll
      for (int j = 0; j < 8; j++) {
        const int e = j * 1024 + tid * 2, row = e >> 7, c8 = e & 127;
        u64x2 p; p[0] = a0[j]; p[1] = a1[j];
        *(u64x2*)(lh_b + swz(row, c8 * 8)) = p;
      }
    }
    __syncthreads();   // BAR1: both tiles staged

    // ---- shared MFMA loop (R3-proven single site): kh0: lh@Whh^T ; kh1: lhp@Wih^T ----
    f32x4 acc[4][2] = {};
    const char* tb = kh ? lhp_b : lh_b;
    const int nks = (kh && LPM == 0) ? 2 : 16;
    for (int ks = 0; ks < nks; ks++) {
      f16x8 af[4];
#pragma unroll
      for (int mi = 0; mi < 4; mi++)
        af[mi] = *(const f16x8*)(tb + swz(mi * 16 + ln, ks * 64 + quad * 16));
#pragma unroll
      for (int mi = 0; mi < 4; mi++)
#pragma unroll
        for (int nb = 0; nb < 2; nb++)
          acc[mi][nb] = __builtin_amdgcn_mfma_f32_16x16x32_f16(af[mi], wf[ks][nb], acc[mi][nb], 0, 0, 0);
    }
    __syncthreads();   // BAR2: all frag reads done -> lg may overwrite lh

    // ---- write partials (quad-XOR column swizzle kills the 4-way write conflict) ----
    {
      float* lg = kh ? lg1 : lg0;
#pragma unroll
      for (int mi = 0; mi < 4; mi++)
#pragma unroll
        for (int nb = 0; nb < 2; nb++)
#pragma unroll
          for (int rr = 0; rr < 4; rr++) {
            const int row = mi * 16 + quad * 4 + rr;
            const int col = g * 32 + nb * 16 + ln;
            lg[row * 128 + (col ^ (((row >> 2) & 7) << 2))] = acc[mi][nb][rr];
          }
    }
    __syncthreads();   // BAR3: partials visible

    // ---- elementwise LSTM update: 4 (row, h-col) states; DUAL-STORE h ----
    const size_t slotoff = ((size_t)l * RING_D + ((t + 1) & (RING_D - 1))) * (BATCH * HD);
    f16* houtM = ringM + slotoff;
    f16* houtL = ringL + slotoff;
#pragma unroll
    for (int s = 0; s < 4; s++) {
      const int row = brow + s * 16;
      const int xm = ((row >> 2) & 7) << 2;
      const int rb = row * 128;
      float g0 = lg0[rb + ((0  + hl_) ^ xm)] + lg1[rb + ((0  + hl_) ^ xm)] + bv0;
      float g1 = lg0[rb + ((32 + hl_) ^ xm)] + lg1[rb + ((32 + hl_) ^ xm)] + bv1;
      float g2 = lg0[rb + ((64 + hl_) ^ xm)] + lg1[rb + ((64 + hl_) ^ xm)] + bv2;
      float g3 = lg0[rb + ((96 + hl_) ^ xm)] + lg1[rb + ((96 + hl_) ^ xm)] + bv3;
      const float igt = 1.f / (1.f + __expf(-g0));
      const float fgt = 1.f / (1.f + __expf(-g1));
      const float ggt = g2 > 0.f ? g2 : (__expf(g2) - 1.f);
      const float ogt = 1.f / (1.f + __expf(-g3));
      cv[s] = fgt * cv[s] + igt * ggt;
      const float hv = ogt * (cv[s] > 0.f ? cv[s] : (__expf(cv[s]) - 1.f));
      f16 hv16 = (f16)hv;
      unsigned short us;
      __builtin_memcpy(&us, &hv16, 2);
      const size_t col = (size_t)(bi * BT + row) * HD + gi * 32 + hl_;
      houtL[col] = hv16;   // plain -> XCD L2 (local consumers)
      __hip_atomic_store((unsigned short*)(houtM + col), us,
                         __ATOMIC_RELAXED, __HIP_MEMORY_SCOPE_AGENT);  // MALL (remote consumers)
      if (l == 2 && t == S_LEN - 1) hlast[col] = hv16;
    }
    __syncthreads();   // BAR4: drains every wave's vmcnt -> both store sets at coherence points
    if (tid == 0)
      __hip_atomic_store(myflag, t + 1, __ATOMIC_RELAXED, __HIP_MEMORY_SCOPE_AGENT);
  }
}

__global__ __launch_bounds__(512, 2) void k_fused(
    const f16* __restrict__ whh,     // [3][2048][512] fp16
    const f16* __restrict__ wih,     // [3] slabs of G4*HD; layer0 packed [2048][64]
    const float* __restrict__ b0,
    const float* __restrict__ b1,
    const float* __restrict__ b2,
    const f16* __restrict__ xin,     // [512*256][64] fp16
    f16* __restrict__ ringM,         // [3][RING_D][256][512] fp16  (MALL ring)
    f16* __restrict__ ringL,         // [3][RING_D][256][512] fp16  (XCD-L2 ring)
    int* __restrict__ flags,         // [3][4][16]
    int* __restrict__ xcdmap,        // [256] published XCC_ID+1
    f16* __restrict__ hlast) {       // [256][512] fp16
  const int tid  = threadIdx.x;
  const int lane = tid & 63;
  const int wave = tid >> 6;
  const int xcd  = blockIdx.x & 7;
  const int slot = blockIdx.x >> 3;   // 0..31
  int l, bi, gi;
  if (xcd < 4) { bi = xcd; l = slot >> 4; gi = slot & 15; }
  else         { if (slot >= 16) return; l = 2; bi = xcd - 4; gi = slot; }
  const int ln = lane & 15;

  __shared__ __align__(16) char smem[131072];

  auto bid_of = [](int ll, int bb, int gg) {
    return (ll == 2) ? ((gg << 3) | (bb + 4)) : ((((ll << 4) + gg) << 3) | bb);
  };

  // --- publish my actual XCD; verify group placement (fallback-safe; R6-proven) ---
  unsigned myxcc;
  asm volatile("s_getreg_b32 %0, hwreg(HW_REG_XCC_ID)" : "=s"(myxcc));
  if (tid == 0)
    __hip_atomic_store(xcdmap + blockIdx.x, (int)myxcc + 1, __ATOMIC_RELAXED, __HIP_MEMORY_SCOPE_AGENT);
  bool lh_local = false, lhp_local = false;
  {
    const int mb = bid_of(l, bi, ln);
    int v = __hip_atomic_load(xcdmap + mb, __ATOMIC_RELAXED, __HIP_MEMORY_SCOPE_AGENT);
    while (!__all(v > 0)) {
      __builtin_amdgcn_s_sleep(2);
      v = __hip_atomic_load(xcdmap + mb, __ATOMIC_RELAXED, __HIP_MEMORY_SCOPE_AGENT);
    }
    lh_local = __all(v == (int)myxcc + 1);
  }
  if (l == 1) {
    const int pb = bid_of(0, bi, ln);
    int v = __hip_atomic_load(xcdmap + pb, __ATOMIC_RELAXED, __HIP_MEMORY_SCOPE_AGENT);
    while (!__all(v > 0)) {
      __builtin_amdgcn_s_sleep(2);
      v = __hip_atomic_load(xcdmap + pb, __ATOMIC_RELAXED, __HIP_MEMORY_SCOPE_AGENT);
    }
    lhp_local = __all(v == (int)myxcc + 1);
  }

  const f16* whh_l = whh + (size_t)l * G4 * HD;
  const f16* wih_l = wih + (size_t)l * G4 * HD;
  const float* bias_l = (l == 0) ? b0 : (l == 1 ? b1 : b2);
  int* fown = flags + l * 64 + bi * 16;
  int* myflag = fown + gi;
  const int* fprev = (l > 0) ? (flags + (l - 1) * 64 + bi * 16) : fown;
  const int* fnext = (l < 2) ? (flags + (l + 1) * 64 + bi * 16) : fown;

  // --- dispatch ONCE into a fully-specialized (R3-CFG) loop ---
  if (l == 0) {
    if (lh_local) lstm_loop<1, 0>(tid, lane, wave, l, bi, gi, whh_l, wih_l, bias_l, xin,
                                  ringM, ringL, fown, myflag, fprev, fnext, hlast, smem);
    else          lstm_loop<0, 0>(tid, lane, wave, l, bi, gi, whh_l, wih_l, bias_l, xin,
                                  ringM, ringL, fown, myflag, fprev, fnext, hlast, smem);
  } else if (l == 1 && lh_local && lhp_local) {
    lstm_loop<1, 1>(tid, lane, wave, l, bi, gi, whh_l, wih_l, bias_l, xin,
                    ringM, ringL, fown, myflag, fprev, fnext, hlast, smem);
  } else if (lh_local) {
    lstm_loop<1, 2>(tid, lane, wave, l, bi, gi, whh_l, wih_l, bias_l, xin,
                    ringM, ringL, fown, myflag, fprev, fnext, hlast, smem);
  } else {
    lstm_loop<0, 2>(tid, lane, wave, l, bi, gi, whh_l, wih_l, bias_l, xin,
                    ringM, ringL, fown, myflag, fprev, fnext, hlast, smem);
  }
}

// ====================== final FC: y[b] = h_last[b,:] . fc_w + fc_b ======================
__global__ __launch_bounds__(64) void k_fc(const f16* __restrict__ hlast,
                                           const float* __restrict__ fcw,
                                           const float* __restrict__ fcb,
                                           float* __restrict__ out) {
  const int b = blockIdx.x, lane = threadIdx.x;
  const f16* hp = hlast + (size_t)b * HD + lane * 8;
  float s = 0.f;
#pragma unroll
  for (int j = 0; j < 8; j++) s += (float)hp[j] * fcw[lane * 8 + j];
  for (int off = 32; off; off >>= 1) s += __shfl_down(s, off);
  if (lane == 0) out[b] = s + fcb[0];
}

// ============================ host ============================
extern "C" void kernel_launch(void* const* d_in, const int* in_sizes, int n_in,
                              void* d_out, int out_size, void* d_ws, size_t ws_size,
                              hipStream_t stream) {
  (void)in_sizes; (void)n_in; (void)out_size; (void)ws_size;
  const float* x      = (const float*)d_in[0];
  const float* wih[3] = {(const float*)d_in[1], (const float*)d_in[4], (const float*)d_in[7]};
  const float* whh[3] = {(const float*)d_in[2], (const float*)d_in[5], (const float*)d_in[8]};
  const float* bia[3] = {(const float*)d_in[3], (const float*)d_in[6], (const float*)d_in[9]};
  const float* fcw = (const float*)d_in[10];
  const float* fcb = (const float*)d_in[11];
  float* out = (float*)d_out;

  char* ws = (char*)d_ws;
  size_t off = 0;
  auto alloc = [&](size_t bytes) -> char* {
    off = (off + 255) & ~(size_t)255;
    char* p = ws + off;
    off += bytes;
    return p;
  };

  f16* xin   = (f16*)alloc((size_t)S_LEN * BATCH * NIN * 2);
  f16* wih16 = (f16*)alloc((size_t)3 * G4 * HD * 2);
  f16* whh16 = (f16*)alloc((size_t)3 * G4 * HD * 2);
  f16* ringM = (f16*)alloc((size_t)3 * RING_D * BATCH * HD * 2);
  f16* ringL = (f16*)alloc((size_t)3 * RING_D * BATCH * HD * 2);
  int* flags = (int*)alloc(256 * 4);
  int* xcdmap= (int*)alloc(256 * 4);
  f16* hlast = (f16*)alloc((size_t)BATCH * HD * 2);

  // ---- prep ----
  {
    int n = S_LEN * BATCH * NIN;
    k_x_transpose<<<dim3(n / 256), dim3(256), 0, stream>>>(x, xin);
  }
  k_f32_to_f16<<<dim3((G4 * NIN + 255) / 256), dim3(256), 0, stream>>>(wih[0], wih16, G4 * NIN);
  k_f32_to_f16<<<dim3((G4 * HD + 255) / 256), dim3(256), 0, stream>>>(wih[1], wih16 + (size_t)G4 * HD, G4 * HD);
  k_f32_to_f16<<<dim3((G4 * HD + 255) / 256), dim3(256), 0, stream>>>(wih[2], wih16 + (size_t)2 * G4 * HD, G4 * HD);
  for (int l = 0; l < 3; l++)
    k_f32_to_f16<<<dim3((G4 * HD + 255) / 256), dim3(256), 0, stream>>>(whh[l], whh16 + (size_t)l * G4 * HD, G4 * HD);
  // zero ring slot 0 of each layer, BOTH rings (h_{-1}=0) + flags + xcdmap
  for (int l = 0; l < 3; l++) {
    k_zero_i32<<<dim3(BATCH * HD / 2 / 256), dim3(256), 0, stream>>>(
        (uint32_t*)(ringM + (size_t)l * RING_D * BATCH * HD), BATCH * HD / 2);
    k_zero_i32<<<dim3(BATCH * HD / 2 / 256), dim3(256), 0, stream>>>(
        (uint32_t*)(ringL + (size_t)l * RING_D * BATCH * HD), BATCH * HD / 2);
  }
  k_zero_i32<<<dim3(1), dim3(256), 0, stream>>>((uint32_t*)flags, 192);
  k_zero_i32<<<dim3(1), dim3(256), 0, stream>>>((uint32_t*)xcdmap, 256);

  // ---- single fused systolic launch: 256 WGs (64 dummies), XCD-colocated groups ----
  k_fused<<<dim3(256), dim3(512), 0, stream>>>(whh16, wih16, bia[0], bia[1], bia[2],
                                               xin, ringM, ringL, flags, xcdmap, hlast);

  // ---- final FC ----
  k_fc<<<dim3(BATCH), dim3(64), 0, stream>>>(hlast, fcw, fcb, out);
}

// Round 8
// 4928.810 us; speedup vs baseline: 1.5190x; 1.5190x over previous
//
#include <hip/hip_runtime.h>
#include <stdint.h>
#include <stddef.h>

#define S_LEN 512
#define BATCH 256
#define NIN   64
#define HD    512
#define G4    2048   // 4*H
#define RING_D 8     // ring depth (pow2); back-pressure enforced at t-6 (provable bound t-7)
#define BT    64     // batch rows per WG

typedef _Float16 f16;
typedef _Float16 f16x8 __attribute__((ext_vector_type(8)));
typedef float    f32x4 __attribute__((ext_vector_type(4)));
typedef uint32_t u32x4 __attribute__((ext_vector_type(4)));
typedef uint64_t u64x2 __attribute__((ext_vector_type(2)));

typedef __attribute__((address_space(3))) void lds_as;
typedef const __attribute__((address_space(1))) void glb_as;

// async global->LDS, 16B/lane, aux=1 = SC0 only: bypass L1, served by the XCD-LOCAL L2.
// Pipelined (no per-op waitcnt) — R7 ERRATA: volatile loads get an s_waitcnt vmcnt(0) after
// EACH access on AMDGPU -> 16 serialized L2 round trips per tile (~3us); this is the async fix.
static __device__ __forceinline__ void gll16_l2(const void* g, void* l) {
  __builtin_amdgcn_global_load_lds((glb_as*)g, (lds_as*)l, 16, 0, 1);
}

// ============================ prep kernels ============================
__global__ void k_f32_to_f16(const float* __restrict__ src, f16* __restrict__ dst, int n) {
  int i = blockIdx.x * 256 + threadIdx.x;
  if (i < n) dst[i] = (f16)src[i];
}

// x [B,S,I] fp32 -> xin [(s*256+b)*64+i] fp16
__global__ void k_x_transpose(const float* __restrict__ x, f16* __restrict__ xin) {
  int idx = blockIdx.x * 256 + threadIdx.x;
  int i  = idx & 63;
  int sb = idx >> 6;
  int b  = sb & 255;
  int s  = sb >> 8;
  xin[idx] = (f16)x[((size_t)b * S_LEN + s) * NIN + i];
}

__global__ void k_zero_i32(uint32_t* p, int n) {
  int i = blockIdx.x * 256 + threadIdx.x;
  if (i < n) p[i] = 0u;
}

// ====================== fused 3-layer systolic LSTM — XCD-local + async L2 staging ======================
// Structure = R7 (template-specialized loop, VGPR=128 no-spill PROVEN).
// Staging = R6 (global_load_lds sc0 from ringL, async/pipelined, PROVEN correct).
// New: STM template flag — producer skips the ringM dual-store when the xcdmap proves ALL its
// consumers are co-XCD (l0 with l1 co-located; l2 always: only own group reads it). Both sides
// decide from the same published map -> consistent; any placement surprise degrades to the
// R3-proven MALL path, never wrongness/deadlock.
//   LHL: 1 = lh staged via gll16_l2 from ringL (XCD L2), 0 = ringM agent atomics (MALL).
//   LPM: 0 = x input (layer0), 1 = prev-h via gll16_l2 from ringL, 2 = prev-h via ringM atomics.
//   STM: 1 = dual-store h to ringM, 0 = ringL only.
// Grid 256 x 512 (64 dummies exit). xcd=blockIdx&7, slot=blockIdx>>3 (HW round-robin):
//   xcd<4 : bi=xcd, l=slot>>4, gi=slot&15   -> (l0,bi)+(l1,bi) pair per XCD
//   xcd>=4: bi=xcd-4, l=2, gi=slot (<16; else dummy)
// MALL steady-state traffic: l2's lhp reads (4MB/step) + l1's ringM stores + flags. Everything
// else is XCD-L2-served.
template<int LHL, int LPM, int STM>
static __device__ __forceinline__ void lstm_loop(
    const int tid, const int lane, const int wave, const int l, const int bi, const int gi,
    const f16* __restrict__ whh_l, const f16* __restrict__ wih_l,
    const float* __restrict__ bias_l, const f16* __restrict__ xin,
    f16* __restrict__ ringM, f16* __restrict__ ringL,
    const int* fown, int* myflag, const int* fprev, const int* fnext,
    f16* __restrict__ hlast, char* smem) {
  const int ln   = lane & 15;
  const int quad = lane >> 4;
  const int g    = wave >> 1;         // gate 0..3
  const int kh   = wave & 1;          // 0: Whh/lh, 1: Wih/lhp

  char*  lh_b  = smem;                   // 64 KiB own h_{t-1} tile (64 rows x 1024B)
  char*  lhp_b = smem + 65536;           // 64 KiB prev h_t tile / x_t tile
  float* lg0   = (float*)smem;           // 32 KiB partial gates (kh=0), aliases lh
  float* lg1   = (float*)(smem + 32768); // 32 KiB partial gates (kh=1), aliases lh

  auto swz = [](int row, int boff) { return row * 1024 + (boff ^ ((row & 7) << 4)); };

  // --- weight fragments -> registers (R3 verbatim; compile-time arm via LPM) ---
  f16x8 wf[16][2];
  if (kh == 0 || LPM != 0) {
    const f16* W = kh ? wih_l : whh_l;
#pragma unroll
    for (int nb = 0; nb < 2; nb++) {
      const int r = g * 512 + gi * 32 + nb * 16 + ln;   // row in [2048, 512]
#pragma unroll
      for (int ks = 0; ks < 16; ks++) {
        u32x4 tmp = *(const u32x4*)(W + (size_t)r * HD + ks * 32 + quad * 8);
        asm volatile("" : "+v"(tmp));
        wf[ks][nb] = __builtin_bit_cast(f16x8, tmp);
      }
    }
  } else {  // layer0, kh==1: Wih1 is [2048][64]
#pragma unroll
    for (int nb = 0; nb < 2; nb++) {
      const int r = g * 512 + gi * 32 + nb * 16 + ln;
#pragma unroll
      for (int ks = 0; ks < 2; ks++) {
        u32x4 tmp = *(const u32x4*)(wih_l + (size_t)r * NIN + ks * 32 + quad * 8);
        asm volatile("" : "+v"(tmp));
        wf[ks][nb] = __builtin_bit_cast(f16x8, tmp);
      }
    }
  }

  // --- per-thread elementwise state: 4 rows x 1 h-col ---
  const int brow = tid >> 5;
  const int hl_  = tid & 31;
  float cv[4] = {0.f, 0.f, 0.f, 0.f};
  const float bv0 = bias_l[0 * HD + gi * 32 + hl_];
  const float bv1 = bias_l[1 * HD + gi * 32 + hl_];
  const float bv2 = bias_l[2 * HD + gi * 32 + hl_];
  const float bv3 = bias_l[3 * HD + gi * 32 + hl_];

  for (int t = 0; t < S_LEN; t++) {
    // ---- all waves poll (quad roles; D=8 -> fnext >= t-6) ----
    {
      const int* fp = fown;
      int need = t;
      if (quad == 1 && LPM != 0)      { fp = fprev; need = t + 1; }
      else if (quad == 2 && l < 2)    { fp = fnext; need = t + 2 - RING_D; }
      int v = __hip_atomic_load(fp + ln, __ATOMIC_RELAXED, __HIP_MEMORY_SCOPE_AGENT);
      while (!__all(v >= need)) {
        __builtin_amdgcn_s_sleep(1);
        v = __hip_atomic_load(fp + ln, __ATOMIC_RELAXED, __HIP_MEMORY_SCOPE_AGENT);
      }
    }
    asm volatile("" ::: "memory");   // keep staging below the poll

    const size_t base = ((size_t)l * RING_D + (t & (RING_D - 1))) * (BATCH * HD)
                      + (size_t)(bi * BT) * HD;

    // ---- stage own h_{t-1} -> lh ----
    if (LHL) {
      const f16* src = ringL + base;
#pragma unroll
      for (int jj = 0; jj < 8; jj++) {
        const int r = wave * 8 + jj;
        const int gb = (lane * 16) ^ ((r & 7) << 4);   // source-side swizzle, LDS dest linear
        gll16_l2((const char*)(src + (size_t)r * HD) + gb, lh_b + r * 1024);
      }
    } else {
      const uint64_t* hown = (const uint64_t*)(ringM + base);
      uint64_t a0[8], a1[8];
#pragma unroll
      for (int j = 0; j < 8; j++) {
        a0[j] = __hip_atomic_load(hown + j * 1024 + tid * 2,     __ATOMIC_RELAXED, __HIP_MEMORY_SCOPE_AGENT);
        a1[j] = __hip_atomic_load(hown + j * 1024 + tid * 2 + 1, __ATOMIC_RELAXED, __HIP_MEMORY_SCOPE_AGENT);
      }
#pragma unroll
      for (int j = 0; j < 8; j++) {
        const int e = j * 1024 + tid * 2, row = e >> 7, c8 = e & 127;
        u64x2 p; p[0] = a0[j]; p[1] = a1[j];
        *(u64x2*)(lh_b + swz(row, c8 * 8)) = p;
      }
    }

    // ---- stage prev h_t (slot (t+1)%D) / x_t -> lhp ----
    if (LPM == 0) {
      const int xr = tid >> 3, xc = tid & 7;   // 64 rows x 8 chunks of 16B
      u32x4 xv = *(const u32x4*)(xin + ((size_t)(t * 256 + bi * BT + xr)) * NIN + xc * 8);
      *(u32x4*)(lhp_b + swz(xr, xc * 16)) = xv;
    } else {
      const size_t pbase = ((size_t)(l - 1) * RING_D + ((t + 1) & (RING_D - 1))) * (BATCH * HD)
                         + (size_t)(bi * BT) * HD;
      if (LPM == 1) {
        const f16* src = ringL + pbase;
#pragma unroll
        for (int jj = 0; jj < 8; jj++) {
          const int r = wave * 8 + jj;
          const int gb = (lane * 16) ^ ((r & 7) << 4);
          gll16_l2((const char*)(src + (size_t)r * HD) + gb, lhp_b + r * 1024);
        }
      } else {
        const uint64_t* hprev = (const uint64_t*)(ringM + pbase);
        uint64_t p0[8], p1[8];
#pragma unroll
        for (int j = 0; j < 8; j++) {
          p0[j] = __hip_atomic_load(hprev + j * 1024 + tid * 2,     __ATOMIC_RELAXED, __HIP_MEMORY_SCOPE_AGENT);
          p1[j] = __hip_atomic_load(hprev + j * 1024 + tid * 2 + 1, __ATOMIC_RELAXED, __HIP_MEMORY_SCOPE_AGENT);
        }
#pragma unroll
        for (int j = 0; j < 8; j++) {
          const int e = j * 1024 + tid * 2, row = e >> 7, c8 = e & 127;
          u64x2 p; p[0] = p0[j]; p[1] = p1[j];
          *(u64x2*)(lhp_b + swz(row, c8 * 8)) = p;
        }
      }
    }
    __syncthreads();   // BAR1: vmcnt+lgkm drained -> both tiles staged (incl. gll DMAs)

    // ---- shared MFMA loop (single site, no-spill proven): kh0: lh@Whh^T ; kh1: lhp@Wih^T ----
    f32x4 acc[4][2] = {};
    const char* tb = kh ? lhp_b : lh_b;
    const int nks = (kh && LPM == 0) ? 2 : 16;
    for (int ks = 0; ks < nks; ks++) {
      f16x8 af[4];
#pragma unroll
      for (int mi = 0; mi < 4; mi++)
        af[mi] = *(const f16x8*)(tb + swz(mi * 16 + ln, ks * 64 + quad * 16));
#pragma unroll
      for (int mi = 0; mi < 4; mi++)
#pragma unroll
        for (int nb = 0; nb < 2; nb++)
          acc[mi][nb] = __builtin_amdgcn_mfma_f32_16x16x32_f16(af[mi], wf[ks][nb], acc[mi][nb], 0, 0, 0);
    }
    __syncthreads();   // BAR2: all frag reads done -> lg may overwrite lh

    // ---- write partials (quad-XOR column swizzle kills the 4-way write conflict) ----
    {
      float* lg = kh ? lg1 : lg0;
#pragma unroll
      for (int mi = 0; mi < 4; mi++)
#pragma unroll
        for (int nb = 0; nb < 2; nb++)
#pragma unroll
          for (int rr = 0; rr < 4; rr++) {
            const int row = mi * 16 + quad * 4 + rr;
            const int col = g * 32 + nb * 16 + ln;
            lg[row * 128 + (col ^ (((row >> 2) & 7) << 2))] = acc[mi][nb][rr];
          }
    }
    __syncthreads();   // BAR3: partials visible

    // ---- elementwise LSTM update: 4 (row, h-col) states; store h (dual iff STM) ----
    const size_t slotoff = ((size_t)l * RING_D + ((t + 1) & (RING_D - 1))) * (BATCH * HD);
    f16* houtM = ringM + slotoff;
    f16* houtL = ringL + slotoff;
#pragma unroll
    for (int s = 0; s < 4; s++) {
      const int row = brow + s * 16;
      const int xm = ((row >> 2) & 7) << 2;
      const int rb = row * 128;
      float g0 = lg0[rb + ((0  + hl_) ^ xm)] + lg1[rb + ((0  + hl_) ^ xm)] + bv0;
      float g1 = lg0[rb + ((32 + hl_) ^ xm)] + lg1[rb + ((32 + hl_) ^ xm)] + bv1;
      float g2 = lg0[rb + ((64 + hl_) ^ xm)] + lg1[rb + ((64 + hl_) ^ xm)] + bv2;
      float g3 = lg0[rb + ((96 + hl_) ^ xm)] + lg1[rb + ((96 + hl_) ^ xm)] + bv3;
      const float igt = 1.f / (1.f + __expf(-g0));
      const float fgt = 1.f / (1.f + __expf(-g1));
      const float ggt = g2 > 0.f ? g2 : (__expf(g2) - 1.f);
      const float ogt = 1.f / (1.f + __expf(-g3));
      cv[s] = fgt * cv[s] + igt * ggt;
      const float hv = ogt * (cv[s] > 0.f ? cv[s] : (__expf(cv[s]) - 1.f));
      f16 hv16 = (f16)hv;
      unsigned short us;
      __builtin_memcpy(&us, &hv16, 2);
      const size_t col = (size_t)(bi * BT + row) * HD + gi * 32 + hl_;
      houtL[col] = hv16;   // plain store, write-through to XCD L2 (local consumers)
      if (STM)
        __hip_atomic_store((unsigned short*)(houtM + col), us,
                           __ATOMIC_RELAXED, __HIP_MEMORY_SCOPE_AGENT);  // MALL (remote consumers)
      if (l == 2 && t == S_LEN - 1) hlast[col] = hv16;
    }
    __syncthreads();   // BAR4: drains every wave's vmcnt -> all h stores at coherence points
    if (tid == 0)
      __hip_atomic_store(myflag, t + 1, __ATOMIC_RELAXED, __HIP_MEMORY_SCOPE_AGENT);
  }
}

__global__ __launch_bounds__(512, 2) void k_fused(
    const f16* __restrict__ whh,     // [3][2048][512] fp16
    const f16* __restrict__ wih,     // [3] slabs of G4*HD; layer0 packed [2048][64]
    const float* __restrict__ b0,
    const float* __restrict__ b1,
    const float* __restrict__ b2,
    const f16* __restrict__ xin,     // [512*256][64] fp16
    f16* __restrict__ ringM,         // [3][RING_D][256][512] fp16  (MALL ring)
    f16* __restrict__ ringL,         // [3][RING_D][256][512] fp16  (XCD-L2 ring)
    int* __restrict__ flags,         // [3][4][16]
    int* __restrict__ xcdmap,        // [256] published XCC_ID+1
    f16* __restrict__ hlast) {       // [256][512] fp16
  const int tid  = threadIdx.x;
  const int lane = tid & 63;
  const int wave = tid >> 6;
  const int xcd  = blockIdx.x & 7;
  const int slot = blockIdx.x >> 3;   // 0..31
  int l, bi, gi;
  if (xcd < 4) { bi = xcd; l = slot >> 4; gi = slot & 15; }
  else         { if (slot >= 16) return; l = 2; bi = xcd - 4; gi = slot; }
  const int ln = lane & 15;

  __shared__ __align__(16) char smem[131072];

  auto bid_of = [](int ll, int bb, int gg) {
    return (ll == 2) ? ((gg << 3) | (bb + 4)) : ((((ll << 4) + gg) << 3) | bb);
  };

  // --- publish my actual XCD ---
  unsigned myxcc;
  asm volatile("s_getreg_b32 %0, hwreg(HW_REG_XCC_ID)" : "=s"(myxcc));
  if (tid == 0)
    __hip_atomic_store(xcdmap + blockIdx.x, (int)myxcc + 1, __ATOMIC_RELAXED, __HIP_MEMORY_SCOPE_AGENT);

  // group_on_my_xcd(ll): poll until the 16 WGs of (ll,bi) published; true iff all on MY xcd.
  auto group_on_my_xcd = [&](int ll) -> bool {
    const int mb = bid_of(ll, bi, ln);
    int v = __hip_atomic_load(xcdmap + mb, __ATOMIC_RELAXED, __HIP_MEMORY_SCOPE_AGENT);
    while (!__all(v > 0)) {
      __builtin_amdgcn_s_sleep(2);
      v = __hip_atomic_load(xcdmap + mb, __ATOMIC_RELAXED, __HIP_MEMORY_SCOPE_AGENT);
    }
    return __all(v == (int)myxcc + 1);
  };

  const f16* whh_l = whh + (size_t)l * G4 * HD;
  const f16* wih_l = wih + (size_t)l * G4 * HD;
  const float* bias_l = (l == 0) ? b0 : (l == 1 ? b1 : b2);
  int* fown = flags + l * 64 + bi * 16;
  int* myflag = fown + gi;
  const int* fprev = (l > 0) ? (flags + (l - 1) * 64 + bi * 16) : fown;
  const int* fnext = (l < 2) ? (flags + (l + 1) * 64 + bi * 16) : fown;

  // --- dispatch ONCE into a fully-specialized (no-spill) loop; decisions from the shared map
  //     are consumer/producer-consistent; fallback = R3-proven MALL path ---
  if (l == 0) {
    const bool grp = group_on_my_xcd(0);
    if (grp) {
      const bool dn = group_on_my_xcd(1);   // l1 consumers co-located -> ringM store unnecessary
      if (dn) lstm_loop<1, 0, 0>(tid, lane, wave, l, bi, gi, whh_l, wih_l, bias_l, xin,
                                 ringM, ringL, fown, myflag, fprev, fnext, hlast, smem);
      else    lstm_loop<1, 0, 1>(tid, lane, wave, l, bi, gi, whh_l, wih_l, bias_l, xin,
                                 ringM, ringL, fown, myflag, fprev, fnext, hlast, smem);
    } else    lstm_loop<0, 0, 1>(tid, lane, wave, l, bi, gi, whh_l, wih_l, bias_l, xin,
                                 ringM, ringL, fown, myflag, fprev, fnext, hlast, smem);
  } else if (l == 1) {
    const bool grp = group_on_my_xcd(1);
    const bool pv  = grp && group_on_my_xcd(0);
    if (pv)       lstm_loop<1, 1, 1>(tid, lane, wave, l, bi, gi, whh_l, wih_l, bias_l, xin,
                                     ringM, ringL, fown, myflag, fprev, fnext, hlast, smem);
    else if (grp) lstm_loop<1, 2, 1>(tid, lane, wave, l, bi, gi, whh_l, wih_l, bias_l, xin,
                                     ringM, ringL, fown, myflag, fprev, fnext, hlast, smem);
    else          lstm_loop<0, 2, 1>(tid, lane, wave, l, bi, gi, whh_l, wih_l, bias_l, xin,
                                     ringM, ringL, fown, myflag, fprev, fnext, hlast, smem);
  } else {
    const bool grp = group_on_my_xcd(2);    // l2 has no downstream: own group is the only reader
    if (grp) lstm_loop<1, 2, 0>(tid, lane, wave, l, bi, gi, whh_l, wih_l, bias_l, xin,
                                ringM, ringL, fown, myflag, fprev, fnext, hlast, smem);
    else     lstm_loop<0, 2, 1>(tid, lane, wave, l, bi, gi, whh_l, wih_l, bias_l, xin,
                                ringM, ringL, fown, myflag, fprev, fnext, hlast, smem);
  }
}

// ====================== final FC: y[b] = h_last[b,:] . fc_w + fc_b ======================
__global__ __launch_bounds__(64) void k_fc(const f16* __restrict__ hlast,
                                           const float* __restrict__ fcw,
                                           const float* __restrict__ fcb,
                                           float* __restrict__ out) {
  const int b = blockIdx.x, lane = threadIdx.x;
  const f16* hp = hlast + (size_t)b * HD + lane * 8;
  float s = 0.f;
#pragma unroll
  for (int j = 0; j < 8; j++) s += (float)hp[j] * fcw[lane * 8 + j];
  for (int off = 32; off; off >>= 1) s += __shfl_down(s, off);
  if (lane == 0) out[b] = s + fcb[0];
}

// ============================ host ============================
extern "C" void kernel_launch(void* const* d_in, const int* in_sizes, int n_in,
                              void* d_out, int out_size, void* d_ws, size_t ws_size,
                              hipStream_t stream) {
  (void)in_sizes; (void)n_in; (void)out_size; (void)ws_size;
  const float* x      = (const float*)d_in[0];
  const float* wih[3] = {(const float*)d_in[1], (const float*)d_in[4], (const float*)d_in[7]};
  const float* whh[3] = {(const float*)d_in[2], (const float*)d_in[5], (const float*)d_in[8]};
  const float* bia[3] = {(const float*)d_in[3], (const float*)d_in[6], (const float*)d_in[9]};
  const float* fcw = (const float*)d_in[10];
  const float* fcb = (const float*)d_in[11];
  float* out = (float*)d_out;

  char* ws = (char*)d_ws;
  size_t off = 0;
  auto alloc = [&](size_t bytes) -> char* {
    off = (off + 255) & ~(size_t)255;
    char* p = ws + off;
    off += bytes;
    return p;
  };

  f16* xin   = (f16*)alloc((size_t)S_LEN * BATCH * NIN * 2);
  f16* wih16 = (f16*)alloc((size_t)3 * G4 * HD * 2);
  f16* whh16 = (f16*)alloc((size_t)3 * G4 * HD * 2);
  f16* ringM = (f16*)alloc((size_t)3 * RING_D * BATCH * HD * 2);
  f16* ringL = (f16*)alloc((size_t)3 * RING_D * BATCH * HD * 2);
  int* flags = (int*)alloc(256 * 4);
  int* xcdmap= (int*)alloc(256 * 4);
  f16* hlast = (f16*)alloc((size_t)BATCH * HD * 2);

  // ---- prep ----
  {
    int n = S_LEN * BATCH * NIN;
    k_x_transpose<<<dim3(n / 256), dim3(256), 0, stream>>>(x, xin);
  }
  k_f32_to_f16<<<dim3((G4 * NIN + 255) / 256), dim3(256), 0, stream>>>(wih[0], wih16, G4 * NIN);
  k_f32_to_f16<<<dim3((G4 * HD + 255) / 256), dim3(256), 0, stream>>>(wih[1], wih16 + (size_t)G4 * HD, G4 * HD);
  k_f32_to_f16<<<dim3((G4 * HD + 255) / 256), dim3(256), 0, stream>>>(wih[2], wih16 + (size_t)2 * G4 * HD, G4 * HD);
  for (int l = 0; l < 3; l++)
    k_f32_to_f16<<<dim3((G4 * HD + 255) / 256), dim3(256), 0, stream>>>(whh[l], whh16 + (size_t)l * G4 * HD, G4 * HD);
  // zero ring slot 0 of each layer, BOTH rings (h_{-1}=0) + flags + xcdmap
  for (int l = 0; l < 3; l++) {
    k_zero_i32<<<dim3(BATCH * HD / 2 / 256), dim3(256), 0, stream>>>(
        (uint32_t*)(ringM + (size_t)l * RING_D * BATCH * HD), BATCH * HD / 2);
    k_zero_i32<<<dim3(BATCH * HD / 2 / 256), dim3(256), 0, stream>>>(
        (uint32_t*)(ringL + (size_t)l * RING_D * BATCH * HD), BATCH * HD / 2);
  }
  k_zero_i32<<<dim3(1), dim3(256), 0, stream>>>((uint32_t*)flags, 192);
  k_zero_i32<<<dim3(1), dim3(256), 0, stream>>>((uint32_t*)xcdmap, 256);

  // ---- single fused systolic launch: 256 WGs (64 dummies), XCD-colocated groups ----
  k_fused<<<dim3(256), dim3(512), 0, stream>>>(whh16, wih16, bia[0], bia[1], bia[2],
                                               xin, ringM, ringL, flags, xcdmap, hlast);

  // ---- final FC ----
  k_fc<<<dim3(BATCH), dim3(64), 0, stream>>>(hlast, fcw, fcb, out);
}